// Round 1
// baseline (308.504 us; speedup 1.0000x reference)
//
#include <hip/hip_runtime.h>
#include <math.h>

#define T_DIM 256
#define V_DIM 4096
#define WIDTH 128

__device__ __forceinline__ float wave_max(float v) {
#pragma unroll
  for (int o = 32; o > 0; o >>= 1) v = fmaxf(v, __shfl_xor(v, o));
  return v;
}

__device__ __forceinline__ double wave_sum(double v) {
#pragma unroll
  for (int o = 32; o > 0; o >>= 1) v += __shfl_xor(v, o);
  return v;
}

// Kernel 1: per-row max / Z / S reductions + per-row MLP -> flag.
__global__ __launch_bounds__(256) void row_stats(
    const float* __restrict__ logits,
    const float* __restrict__ w1, const float* __restrict__ b1,
    const float* __restrict__ w2, const float* __restrict__ b2,
    float* __restrict__ row_max, double* __restrict__ row_Z,
    double* __restrict__ row_flag) {
  const int row = blockIdx.x;
  const int t = row & (T_DIM - 1);
  const int tid = threadIdx.x;
  const int lane = tid & 63;
  const int wave = tid >> 6;

  const float4* src = (const float4*)(logits + (size_t)row * V_DIM);
  float4 xv[4];
#pragma unroll
  for (int k = 0; k < 4; ++k) xv[k] = src[tid + k * 256];

  float m = -INFINITY;
#pragma unroll
  for (int k = 0; k < 4; ++k)
    m = fmaxf(m, fmaxf(fmaxf(xv[k].x, xv[k].y), fmaxf(xv[k].z, xv[k].w)));
  m = wave_max(m);

  __shared__ float smax[4];
  __shared__ double szs[4], sss[4];
  if (lane == 0) smax[wave] = m;
  __syncthreads();
  m = fmaxf(fmaxf(smax[0], smax[1]), fmaxf(smax[2], smax[3]));

  // Z = sum e^{x-m}; S = sum (x-m) e^{x-m}; accumulate in double for the
  // downstream entropy->sigmoid->cumprod chain (absmax budget 3.8e-6).
  double z = 0.0, s = 0.0;
#pragma unroll
  for (int k = 0; k < 4; ++k) {
    float vals[4] = {xv[k].x, xv[k].y, xv[k].z, xv[k].w};
#pragma unroll
    for (int j = 0; j < 4; ++j) {
      float sv = vals[j] - m;
      float ev = expf(sv);
      z += (double)ev;
      s += (double)ev * (double)sv;
    }
  }
  z = wave_sum(z);
  s = wave_sum(s);
  if (lane == 0) { szs[wave] = z; sss[wave] = s; }
  __syncthreads();

  if (wave == 0) {
    z = szs[0] + szs[1] + szs[2] + szs[3];
    s = sss[0] + sss[1] + sss[2] + sss[3];
    if (lane == 0) { row_max[row] = m; row_Z[row] = z; }
    if (t < T_DIM - 1) {
      double H = log(z) - s / z;                 // entropy
      double nrm = 2.0 * H / log(256.0) - 1.0;   // entropy_max = log(T)
      // MLP: 128 hidden units, 2 per lane of wave 0.
      double acc = 0.0;
#pragma unroll
      for (int j = lane; j < WIDTH; j += 64) {
        double h = nrm * (double)w1[j] + (double)b1[j];
        h = h > 0.0 ? h : 0.0;
        acc += h * (double)w2[j];
      }
      acc = wave_sum(acc);
      if (lane == 0) {
        double lin = 2.0 * acc + (double)b2[0];
        double xx = lin - log((double)(T_DIM - 1 - t));  // ns = T-1-t
        row_flag[row] = 1.0 / (1.0 + exp(-xx));
      }
    }
  }
}

// Kernel 2: per-batch sequential cumprod -> scale[b,t] = f[t+1]*resid[t]/Z[t]
__global__ void cumprod_k(const double* __restrict__ row_Z,
                          const double* __restrict__ row_flag,
                          float* __restrict__ row_scale, int Bn) {
  int b = blockIdx.x * blockDim.x + threadIdx.x;
  if (b >= Bn) return;
  const double* f = row_flag + (size_t)b * T_DIM;  // f[t] = flags[b, t+1], t<T-1
  const double* Z = row_Z + (size_t)b * T_DIM;
  float* sc = row_scale + (size_t)b * T_DIM;
  double r = 1.0;
  for (int t = 0; t < T_DIM; ++t) {
    double ft = (t == 0) ? 0.0 : f[t - 1];          // flags[b, t]
    r *= (1.0 - ft);                                // residual[b, t]
    double ftp1 = (t == T_DIM - 1) ? 1.0 : f[t];    // flags[b, t+1]
    sc[t] = (float)(ftp1 * r / Z[t]);
  }
}

// Kernel 3: out = expf(x - max) * scale
__global__ __launch_bounds__(256) void out_k(const float* __restrict__ logits,
                                             const float* __restrict__ row_max,
                                             const float* __restrict__ row_scale,
                                             float* __restrict__ out) {
  const int row = blockIdx.x;
  const int tid = threadIdx.x;
  const float m = row_max[row];
  const float sc = row_scale[row];
  const float4* src = (const float4*)(logits + (size_t)row * V_DIM);
  float4* dst = (float4*)(out + (size_t)row * V_DIM);
#pragma unroll
  for (int k = 0; k < 4; ++k) {
    float4 x = src[tid + k * 256];
    float4 o;
    o.x = expf(x.x - m) * sc;
    o.y = expf(x.y - m) * sc;
    o.z = expf(x.z - m) * sc;
    o.w = expf(x.w - m) * sc;
    dst[tid + k * 256] = o;
  }
}

extern "C" void kernel_launch(void* const* d_in, const int* in_sizes, int n_in,
                              void* d_out, int out_size, void* d_ws, size_t ws_size,
                              hipStream_t stream) {
  const float* logits = (const float*)d_in[0];
  const float* w1 = (const float*)d_in[1];
  const float* b1 = (const float*)d_in[2];
  const float* w2 = (const float*)d_in[3];
  const float* b2 = (const float*)d_in[4];
  float* out = (float*)d_out;

  const size_t nrows = (size_t)in_sizes[0] / V_DIM;  // B*T = 8192
  const int Bn = (int)(nrows / T_DIM);               // 32

  // Workspace layout (doubles first for alignment): 24 B/row = 196 KB total.
  double* row_Z = (double*)d_ws;
  double* row_flag = row_Z + nrows;
  float* row_max = (float*)(row_flag + nrows);
  float* row_scale = row_max + nrows;

  row_stats<<<(int)nrows, 256, 0, stream>>>(logits, w1, b1, w2, b2,
                                            row_max, row_Z, row_flag);
  cumprod_k<<<1, 64, 0, stream>>>(row_Z, row_flag, row_scale, Bn);
  out_k<<<(int)nrows, 256, 0, stream>>>(logits, row_max, row_scale, out);
}

// Round 2
// 263.473 us; speedup vs baseline: 1.1709x; 1.1709x over previous
//
#include <hip/hip_runtime.h>
#include <math.h>

#define T_DIM 256
#define V_DIM 4096
#define WIDTH 128

__device__ __forceinline__ float wave_max_f(float v) {
#pragma unroll
  for (int o = 32; o > 0; o >>= 1) v = fmaxf(v, __shfl_xor(v, o));
  return v;
}

__device__ __forceinline__ float wave_sum_f(float v) {
#pragma unroll
  for (int o = 32; o > 0; o >>= 1) v += __shfl_xor(v, o);
  return v;
}

__device__ __forceinline__ double wave_sum_d(double v) {
#pragma unroll
  for (int o = 32; o > 0; o >>= 1) v += __shfl_xor(v, o);
  return v;
}

// Kernel 1: per-row max / Z / S reductions + per-row MLP -> flag.
// fp32 in the hot loop; fp64 only in the per-row scalar tail.
__global__ __launch_bounds__(256) void row_stats(
    const float* __restrict__ logits,
    const float* __restrict__ w1, const float* __restrict__ b1,
    const float* __restrict__ w2, const float* __restrict__ b2,
    float* __restrict__ row_max, double* __restrict__ row_Z,
    double* __restrict__ row_flag) {
  const int row = blockIdx.x;
  const int t = row & (T_DIM - 1);
  const int tid = threadIdx.x;
  const int lane = tid & 63;
  const int wave = tid >> 6;

  const float4* src = (const float4*)(logits + (size_t)row * V_DIM);
  float4 xv[4];
#pragma unroll
  for (int k = 0; k < 4; ++k) xv[k] = src[tid + k * 256];

  float m = -INFINITY;
#pragma unroll
  for (int k = 0; k < 4; ++k)
    m = fmaxf(m, fmaxf(fmaxf(xv[k].x, xv[k].y), fmaxf(xv[k].z, xv[k].w)));
  m = wave_max_f(m);

  __shared__ float smax[4];
  __shared__ float szs[4], sss[4];
  if (lane == 0) smax[wave] = m;
  __syncthreads();
  m = fmaxf(fmaxf(smax[0], smax[1]), fmaxf(smax[2], smax[3]));

  // Z = sum e^{x-m}; S = sum (x-m) e^{x-m}  (fp32 accumulate, ~2e-7 rel err;
  // downstream amplification analysis: <3e-7 absolute on output vs 3.8e-6 budget)
  float z = 0.f, s = 0.f;
#pragma unroll
  for (int k = 0; k < 4; ++k) {
    float vals[4] = {xv[k].x, xv[k].y, xv[k].z, xv[k].w};
#pragma unroll
    for (int j = 0; j < 4; ++j) {
      float sv = vals[j] - m;
      float ev = expf(sv);
      z += ev;
      s = fmaf(ev, sv, s);
    }
  }
  z = wave_sum_f(z);
  s = wave_sum_f(s);
  if (lane == 0) { szs[wave] = z; sss[wave] = s; }
  __syncthreads();

  if (wave == 0 && lane == 0) {
    double zd = (double)szs[0] + szs[1] + szs[2] + szs[3];
    double sd = (double)sss[0] + sss[1] + sss[2] + sss[3];
    row_max[row] = m;
    row_Z[row] = zd;
    if (t < T_DIM - 1) {
      double H = log(zd) - sd / zd;              // entropy
      double nrm = 2.0 * H / log(256.0) - 1.0;   // entropy_max = log(T)
      double acc = 0.0;
#pragma unroll 4
      for (int j = 0; j < WIDTH; ++j) {
        double h = nrm * (double)w1[j] + (double)b1[j];
        h = h > 0.0 ? h : 0.0;
        acc += h * (double)w2[j];
      }
      double lin = 2.0 * acc + (double)b2[0];
      double xx = lin - log((double)(T_DIM - 1 - t));  // ns = T-1-t
      row_flag[row] = 1.0 / (1.0 + exp(-xx));
    }
  }
}

// Kernel 2: per-batch cumprod as a wave-parallel scan.
// scale[b,t] = flags[b,t+1] * residual[b,t] / Z[b,t]
// residual[b,t] = prod_{i<=t} (1 - flags[b,i]); flags[b,0]=0, flags[b,256]=1.
__global__ __launch_bounds__(64) void cumprod_scan(
    const double* __restrict__ row_Z, const double* __restrict__ row_flag,
    float* __restrict__ row_scale) {
  const int b = blockIdx.x;
  const int lane = threadIdx.x;  // 64 lanes, 4 t-values each
  __shared__ double fl[T_DIM];   // fl[t] = flags[b, t+1]

  const double* fb = row_flag + (size_t)b * T_DIM;
  const double* Zb = row_Z + (size_t)b * T_DIM;

#pragma unroll
  for (int j = lane; j < T_DIM; j += 64) fl[j] = (j == T_DIM - 1) ? 1.0 : fb[j];
  __syncthreads();

  // lane-local running product over its 4 consecutive t values
  double loc[4];
  double p = 1.0;
#pragma unroll
  for (int j = 0; j < 4; ++j) {
    int t = lane * 4 + j;
    double flag_t = (t == 0) ? 0.0 : fl[t - 1];  // flags[b, t]
    p *= (1.0 - flag_t);
    loc[j] = p;
  }
  // inclusive scan (product) across 64 lanes
  double inc = p;
#pragma unroll
  for (int o = 1; o < 64; o <<= 1) {
    double up = __shfl_up(inc, o);
    if (lane >= o) inc *= up;
  }
  double exc = __shfl_up(inc, 1);
  if (lane == 0) exc = 1.0;

#pragma unroll
  for (int j = 0; j < 4; ++j) {
    int t = lane * 4 + j;
    double resid = exc * loc[j];
    row_scale[(size_t)b * T_DIM + t] = (float)(fl[t] * resid / Zb[t]);
  }
}

// Kernel 3: out = expf(x - max) * scale
__global__ __launch_bounds__(256) void out_k(const float* __restrict__ logits,
                                             const float* __restrict__ row_max,
                                             const float* __restrict__ row_scale,
                                             float* __restrict__ out) {
  const int row = blockIdx.x;
  const int tid = threadIdx.x;
  const float m = row_max[row];
  const float sc = row_scale[row];
  const float4* src = (const float4*)(logits + (size_t)row * V_DIM);
  float4* dst = (float4*)(out + (size_t)row * V_DIM);
#pragma unroll
  for (int k = 0; k < 4; ++k) {
    float4 x = src[tid + k * 256];
    float4 o;
    o.x = expf(x.x - m) * sc;
    o.y = expf(x.y - m) * sc;
    o.z = expf(x.z - m) * sc;
    o.w = expf(x.w - m) * sc;
    dst[tid + k * 256] = o;
  }
}

extern "C" void kernel_launch(void* const* d_in, const int* in_sizes, int n_in,
                              void* d_out, int out_size, void* d_ws, size_t ws_size,
                              hipStream_t stream) {
  const float* logits = (const float*)d_in[0];
  const float* w1 = (const float*)d_in[1];
  const float* b1 = (const float*)d_in[2];
  const float* w2 = (const float*)d_in[3];
  const float* b2 = (const float*)d_in[4];
  float* out = (float*)d_out;

  const size_t nrows = (size_t)in_sizes[0] / V_DIM;  // B*T = 8192
  const int Bn = (int)(nrows / T_DIM);               // 32

  // Workspace layout (doubles first for alignment): 24 B/row ~= 196 KB total.
  double* row_Z = (double*)d_ws;
  double* row_flag = row_Z + nrows;
  float* row_max = (float*)(row_flag + nrows);
  float* row_scale = row_max + nrows;

  row_stats<<<(int)nrows, 256, 0, stream>>>(logits, w1, b1, w2, b2,
                                            row_max, row_Z, row_flag);
  cumprod_scan<<<Bn, 64, 0, stream>>>(row_Z, row_flag, row_scale);
  out_k<<<(int)nrows, 256, 0, stream>>>(logits, row_max, row_scale, out);
}